// Round 5
// baseline (359.546 us; speedup 1.0000x reference)
//
#include <hip/hip_runtime.h>
#include <cstdint>

namespace {

constexpr int BPB  = 64;     // batches per block
constexpr int NTHR = 256;    // 4 waves: 0=bwd-outer 1=bwd-inner 2=fwd-inner 3=fwd-outer
constexpr int RSTR = 37;     // LDS row stride (floats); lane*37 mod 32 = lane*5 -> conflict-free
constexpr int ROWF = 567;    // floats per R_mode batch row
constexpr int OUTF = 192;    // floats per output batch row
constexpr int WSPAN = BPB * RSTR;   // 2368 floats per-wave staging

__device__ __forceinline__ float sigm_(float x){ return __fdividef(1.f, 1.f+__expf(-x)); }
__device__ __forceinline__ float tanh_(float x){ return __fdividef(2.f, 1.f+__expf(-2.f*x)) - 1.f; }

__device__ __forceinline__ void lds_fence(){
    asm volatile("s_waitcnt lgkmcnt(0)" ::: "memory");
    __builtin_amdgcn_sched_barrier(0);
}

__device__ __forceinline__ void flush16(float* __restrict__ dst, const float* __restrict__ buf){
    #pragma unroll
    for (int q = 0; q < 4; ++q)
        *reinterpret_cast<float4*>(dst + 4*q) =
            make_float4(buf[4*q+0], buf[4*q+1], buf[4*q+2], buf[4*q+3]);
}

// ROLE 0: bwd-outer  t=15..0  (M<-M@R^T), save u(t)=M*dir; post: d[t]=Mf1@u(t) -> floats 0..47
// ROLE 1: bwd-inner  t=31..16 (M<-M@R^T), d[t]=M*dir -> floats 48..95; publish Mf1
// ROLE 2: fwd-inner  t=32..46 (M<-M@R),   out[t+1]=M*dir -> floats 99..143 (+seed 96..98=dir); publish Pf2
// ROLE 3: fwd-outer  t=47..62 (M<-M@R),   save q(t)=M*dir; post: out[t+1]=Pf2@q(t) -> floats 144..191
template<int ROLE>
__device__ __forceinline__ void run_chain(const float* __restrict__ Rg,
                                          const float* __restrict__ dirg,
                                          float* __restrict__ outg,
                                          int64_t b0, int lane,
                                          float* __restrict__ ldsAll)
{
    float* const L = ldsAll + ROLE * WSPAN;
    const float* rbase = Rg + b0 * (int64_t)ROWF;
    const int64_t b = b0 + lane;
    const float dx = dirg[b*3+0], dy = dirg[b*3+1], dz = dirg[b*3+2];
    float* orow = outg + b * OUTF;

    // lane-constant (seg,off) decomposition of the 9 staging float4s; chunk base is an imm
    int voff[9], lwr[9];
    #pragma unroll
    for (int k = 0; k < 9; ++k) {
        const int f4 = k*64 + lane, seg = f4/9, off = f4 - seg*9;
        voff[k] = seg*ROWF + off*4;   // float offset into block's rows
        lwr[k]  = seg*RSTR + off*4;   // float offset into this wave's LDS
    }

    float4 pf[9];
    auto issue = [&](int t0f) {
        #pragma unroll
        for (int k = 0; k < 9; ++k)
            pf[k] = *reinterpret_cast<const float4*>(rbase + voff[k] + t0f);
    };
    auto stw = [&]() {
        #pragma unroll
        for (int k = 0; k < 9; ++k) {
            float* p = L + lwr[k];
            p[0]=pf[k].x; p[1]=pf[k].y; p[2]=pf[k].z; p[3]=pf[k].w;
        }
    };

    constexpr int TBL[4][4] = {
        {108, 72, 36, 0},        // role0: t0 = 12, 8, 4, 0   (processed descending)
        {252, 216, 180, 144},    // role1: t0 = 28,24,20,16
        {288, 324, 360, 396},    // role2: t0 = 32,36,40,44 (last chunk uses 3 of 4)
        {423, 459, 495, 531}};   // role3: t0 = 47,51,55,59

    float M[9] = {1.f,0.f,0.f, 0.f,1.f,0.f, 0.f,0.f,1.f};
    float vv[48];                 // roles 0,3 (DCE'd otherwise)
    float bufE[16], bufO[16];     // roles 1,2 (DCE'd otherwise)

    #define PUT3(F0, VX, VY, VZ)                                          \
        do {                                                              \
            { const int f_=(F0);   if ((((f_>>4)&1)==0)) bufE[f_&15]=(VX); else bufO[f_&15]=(VX); } \
            { const int f_=(F0)+1; if ((((f_>>4)&1)==0)) bufE[f_&15]=(VY); else bufO[f_&15]=(VY); } \
            { const int f_=(F0)+2; if ((((f_>>4)&1)==0)) bufE[f_&15]=(VZ); else bufO[f_&15]=(VZ); } \
        } while (0)

    if constexpr (ROLE == 2) PUT3(96, dx, dy, dz);   // t=32 slot placeholder (lstm overwrites)

    issue(TBL[ROLE][0]);
    stw();
    issue(TBL[ROLE][1]);
    lds_fence();

    #pragma unroll
    for (int c = 0; c < 4; ++c) {
        #pragma unroll
        for (int s = 0; s < 4; ++s) {
            const int tt = (ROLE <= 1) ? 3 - s : s;     // inner order matches chain direction
            const int t  = (ROLE == 0) ? (12 - 4*c) + tt
                         : (ROLE == 1) ? (28 - 4*c) + tt
                         : (ROLE == 2) ? 32 + 4*c + tt
                         :               47 + 4*c + tt;
            if (ROLE == 2 && t > 46) continue;          // folds at compile time

            const float* Rl = L + lane*RSTR + tt*9;
            const float r0=Rl[0], r1=Rl[1], r2=Rl[2];
            const float r3=Rl[3], r4=Rl[4], r5=Rl[5];
            const float r6=Rl[6], r7=Rl[7], r8=Rl[8];
            #pragma unroll
            for (int row = 0; row < 3; ++row) {
                const float a0=M[3*row], a1=M[3*row+1], a2=M[3*row+2];
                float n0, n1, n2;
                if constexpr (ROLE <= 1) {      // M <- M @ R^T
                    n0 = a0*r0 + a1*r1 + a2*r2;
                    n1 = a0*r3 + a1*r4 + a2*r5;
                    n2 = a0*r6 + a1*r7 + a2*r8;
                } else {                        // M <- M @ R
                    n0 = a0*r0 + a1*r3 + a2*r6;
                    n1 = a0*r1 + a1*r4 + a2*r7;
                    n2 = a0*r2 + a1*r5 + a2*r8;
                }
                M[3*row]=n0; M[3*row+1]=n1; M[3*row+2]=n2;
            }
            const float wx = M[0]*dx + M[1]*dy + M[2]*dz;
            const float wy = M[3]*dx + M[4]*dy + M[5]*dz;
            const float wz = M[6]*dx + M[7]*dy + M[8]*dz;

            if constexpr (ROLE == 0) {
                vv[3*t]=wx; vv[3*t+1]=wy; vv[3*t+2]=wz;
            } else if constexpr (ROLE == 1) {
                PUT3(3*t, wx, wy, wz);                  // floats 48..95, t descending
                if (t == 26) flush16(orow + 80, bufO);  // sector 5 complete
                if (t == 21) flush16(orow + 64, bufE);  // sector 4
                if (t == 16) flush16(orow + 48, bufO);  // sector 3
            } else if constexpr (ROLE == 2) {
                PUT3(3*t + 3, wx, wy, wz);              // floats 99..143, t ascending
                if (t == 36) flush16(orow +  96, bufE); // sector 6 (96..111)
                if (t == 41) flush16(orow + 112, bufO); // sector 7
                if (t == 46) flush16(orow + 128, bufE); // sector 8
            } else {
                vv[3*(t-47)]=wx; vv[3*(t-47)+1]=wy; vv[3*(t-47)+2]=wz;
            }
        }
        if (c < 3) {
            lds_fence();                // chunk-c reads done before overwrite (cheap: values consumed)
            stw();                      // stage chunk c+1 (compiler inserts vmcnt wait)
            if (c < 2) issue(TBL[ROLE][c+2]);
            lds_fence();                // writes visible before next chunk's reads
        }
    }

    if constexpr (ROLE == 1 || ROLE == 2) {     // publish final matrix in own staging
        lds_fence();
        float* P = L + lane*RSTR;
        #pragma unroll
        for (int i = 0; i < 9; ++i) P[i] = M[i];
    }

    __syncthreads();    // each wave executes exactly one barrier

    if constexpr (ROLE == 0 || ROLE == 3) {
        const float* P = ldsAll + (ROLE == 0 ? 1 : 2) * WSPAN + lane*RSTR;
        const float m0=P[0], m1=P[1], m2=P[2];
        const float m3=P[3], m4=P[4], m5=P[5];
        const float m6=P[6], m7=P[7], m8=P[8];
        #pragma unroll
        for (int i = 0; i < 16; ++i) {
            const float x=vv[3*i], y=vv[3*i+1], z=vv[3*i+2];
            vv[3*i]   = m0*x + m1*y + m2*z;
            vv[3*i+1] = m3*x + m4*y + m5*z;
            vv[3*i+2] = m6*x + m7*y + m8*z;
        }
        float* dst = orow + (ROLE == 0 ? 0 : 144);
        #pragma unroll
        for (int q = 0; q < 12; ++q)
            *reinterpret_cast<float4*>(dst + 4*q) =
                make_float4(vv[4*q], vv[4*q+1], vv[4*q+2], vv[4*q+3]);
    }
    #undef PUT3
}

__global__ __launch_bounds__(NTHR, 4) void gaze_kernel(
    const float* __restrict__ dirg, const float* __restrict__ Rg,
    float* __restrict__ outg)
{
    __shared__ float ldsR[4 * WSPAN];   // 37888 B -> 4 blocks/CU -> 16 waves/CU
    const int tid = threadIdx.x, wid = tid >> 6, lane = tid & 63;
    const int64_t b0 = (int64_t)blockIdx.x * BPB;
    if      (wid == 0) run_chain<0>(Rg, dirg, outg, b0, lane, ldsR);
    else if (wid == 1) run_chain<1>(Rg, dirg, outg, b0, lane, ldsR);
    else if (wid == 2) run_chain<2>(Rg, dirg, outg, b0, lane, ldsR);
    else               run_chain<3>(Rg, dirg, outg, b0, lane, ldsR);
}

// ---- kernel 2: LSTM over dirs[0..32] (row floats 0..98, L2/L3-warm); writes h into 96..98
__global__ __launch_bounds__(64) void lstm_kernel(
    const float* __restrict__ w_ih, const float* __restrict__ w_hh,
    const float* __restrict__ b_ih, const float* __restrict__ b_hh,
    float* __restrict__ outg)
{
    __shared__ float sd[64 * 101];      // 64 rows x 100 floats (+1 pad)
    const int lane = threadIdx.x;       // one wave per block
    const int64_t b0 = (int64_t)blockIdx.x * 64;

    #pragma unroll
    for (int k = 0; k < 25; ++k) {      // 1600 float4: coalesced 400-B runs per row
        const int f4 = k*64 + lane, seg = f4/25, off = f4 - seg*25;
        const float4 v = *reinterpret_cast<const float4*>(outg + (b0+seg)*OUTF + off*4);
        float* p = sd + seg*101 + off*4;
        p[0]=v.x; p[1]=v.y; p[2]=v.z; p[3]=v.w;
    }
    lds_fence();

    float wi[12][3], wh[12][3], bs[12];
    #pragma unroll
    for (int g = 0; g < 12; ++g) {      // uniform -> scalar loads
        wi[g][0]=w_ih[g*3+0]; wi[g][1]=w_ih[g*3+1]; wi[g][2]=w_ih[g*3+2];
        wh[g][0]=w_hh[g*3+0]; wh[g][1]=w_hh[g*3+1]; wh[g][2]=w_hh[g*3+2];
        bs[g]   = b_ih[g] + b_hh[g];
    }

    const float* x = sd + lane*101;     // stride 101: lane*5 mod 32 -> ~conflict-free
    float h[3]  = {0.f,0.f,0.f};
    float cc[3] = {0.f,0.f,0.f};
    #pragma unroll
    for (int t = 0; t < 33; ++t) {
        const float x0 = x[3*t], x1 = x[3*t+1], x2 = x[3*t+2];
        float ga[12];
        #pragma unroll
        for (int g = 0; g < 12; ++g)
            ga[g] = bs[g] + wi[g][0]*x0 + wi[g][1]*x1 + wi[g][2]*x2
                          + wh[g][0]*h[0] + wh[g][1]*h[1] + wh[g][2]*h[2];
        float ig[3], fg[3], gg[3], og[3];
        #pragma unroll
        for (int j = 0; j < 3; ++j) {
            ig[j] = sigm_(ga[j]);
            fg[j] = sigm_(ga[3+j]);
            gg[j] = tanh_(ga[6+j]);
            og[j] = sigm_(ga[9+j]);
        }
        #pragma unroll
        for (int j = 0; j < 3; ++j) {
            cc[j] = fg[j]*cc[j] + ig[j]*gg[j];
            h[j]  = og[j]*tanh_(cc[j]);
        }
    }

    float* row = outg + (b0 + lane) * OUTF;
    row[96] = h[0]; row[97] = h[1]; row[98] = h[2];
}

}  // namespace

extern "C" void kernel_launch(void* const* d_in, const int* in_sizes, int n_in,
                              void* d_out, int out_size, void* d_ws, size_t ws_size,
                              hipStream_t stream) {
    const float* dirg = (const float*)d_in[0];
    const float* Rg   = (const float*)d_in[1];
    // d_in[2] = S_diag: unused by the reference forward
    const float* wih  = (const float*)d_in[3];
    const float* whh  = (const float*)d_in[4];
    const float* bih  = (const float*)d_in[5];
    const float* bhh  = (const float*)d_in[6];
    float* outg = (float*)d_out;

    const int B = in_sizes[0] / 3;      // 65536
    gaze_kernel<<<B / BPB, NTHR, 0, stream>>>(dirg, Rg, outg);
    lstm_kernel<<<B / 64, 64, 0, stream>>>(wih, whh, bih, bhh, outg);
}

// Round 6
// 309.694 us; speedup vs baseline: 1.1610x; 1.1610x over previous
//
#include <hip/hip_runtime.h>
#include <cstdint>

namespace {

constexpr int BPB  = 64;     // batches per block
constexpr int NTHR = 256;    // 4 waves: 0=bwd-outer 1=bwd-inner 2=fwd-inner 3=fwd-outer
constexpr int RSTR = 37;     // LDS row stride (floats); lane*37 mod 32 = lane*5 -> conflict-free
constexpr int ROWF = 567;    // floats per R_mode batch row
constexpr int OUTF = 192;    // floats per output batch row
constexpr int WSPAN = BPB * RSTR;   // 2368 floats per-wave staging

__device__ __forceinline__ float sigm_(float x){ return __fdividef(1.f, 1.f+__expf(-x)); }
__device__ __forceinline__ float tanh_(float x){ return __fdividef(2.f, 1.f+__expf(-2.f*x)) - 1.f; }

__device__ __forceinline__ void lds_fence(){
    asm volatile("s_waitcnt lgkmcnt(0)" ::: "memory");
    __builtin_amdgcn_sched_barrier(0);
}

__device__ __forceinline__ void flush16(float* __restrict__ dst, const float* __restrict__ buf){
    #pragma unroll
    for (int q = 0; q < 4; ++q)
        *reinterpret_cast<float4*>(dst + 4*q) =
            make_float4(buf[4*q+0], buf[4*q+1], buf[4*q+2], buf[4*q+3]);
}

// ROLE 0: bwd-outer  t=15..0  (M<-M@R^T): stream u(t)=M*dir -> floats 0..47;  fixup by Mf1 after barrier
// ROLE 1: bwd-inner  t=31..16 (M<-M@R^T): d[t]=M*dir -> floats 48..95; publish Mf1 in LDS
// ROLE 2: fwd-inner  t=32..46 (M<-M@R):   out[t+1]=M*dir -> floats 99..143 (+seed 96..98=dir); publish Pf2
// ROLE 3: fwd-outer  t=47..62 (M<-M@R):   stream q(t)=M*dir -> floats 144..191; fixup by Pf2 after barrier
template<int ROLE>
__device__ __forceinline__ void run_chain(const float* __restrict__ Rg,
                                          const float* __restrict__ dirg,
                                          float* __restrict__ outg,
                                          int64_t b0, int lane,
                                          float* __restrict__ ldsAll)
{
    float* const L = ldsAll + ROLE * WSPAN;
    const float* rbase = Rg + b0 * (int64_t)ROWF;
    const int64_t b = b0 + lane;
    const float dx = dirg[b*3+0], dy = dirg[b*3+1], dz = dirg[b*3+2];
    float* orow = outg + b * OUTF;

    // lane-constant (seg,off) decomposition of the 9 staging float4s; chunk base is an imm
    int voff[9], lwr[9];
    #pragma unroll
    for (int k = 0; k < 9; ++k) {
        const int f4 = k*64 + lane, seg = f4/9, off = f4 - seg*9;
        voff[k] = seg*ROWF + off*4;   // float offset into block's rows
        lwr[k]  = seg*RSTR + off*4;   // float offset into this wave's LDS
    }

    float4 pf[9];
    auto issue = [&](int t0f) {
        #pragma unroll
        for (int k = 0; k < 9; ++k)
            pf[k] = *reinterpret_cast<const float4*>(rbase + voff[k] + t0f);
    };
    auto stw = [&]() {
        #pragma unroll
        for (int k = 0; k < 9; ++k) {
            float* p = L + lwr[k];
            p[0]=pf[k].x; p[1]=pf[k].y; p[2]=pf[k].z; p[3]=pf[k].w;
        }
    };

    constexpr int TBL[4][4] = {
        {108, 72, 36, 0},        // role0: t0 = 12, 8, 4, 0   (processed descending)
        {252, 216, 180, 144},    // role1: t0 = 28,24,20,16
        {288, 324, 360, 396},    // role2: t0 = 32,36,40,44 (last chunk uses 3 of 4)
        {423, 459, 495, 531}};   // role3: t0 = 47,51,55,59

    float M[9] = {1.f,0.f,0.f, 0.f,1.f,0.f, 0.f,0.f,1.f};
    float bufE[16], bufO[16];     // 64-B sector staging, all roles (compile-time idx only)

    #define PUT3(F0, VX, VY, VZ)                                          \
        do {                                                              \
            { const int f_=(F0);   if ((((f_>>4)&1)==0)) bufE[f_&15]=(VX); else bufO[f_&15]=(VX); } \
            { const int f_=(F0)+1; if ((((f_>>4)&1)==0)) bufE[f_&15]=(VY); else bufO[f_&15]=(VY); } \
            { const int f_=(F0)+2; if ((((f_>>4)&1)==0)) bufE[f_&15]=(VZ); else bufO[f_&15]=(VZ); } \
        } while (0)

    if constexpr (ROLE == 2) PUT3(96, dx, dy, dz);   // t=32 slot placeholder (lstm overwrites)

    issue(TBL[ROLE][0]);
    stw();
    issue(TBL[ROLE][1]);
    lds_fence();

    #pragma unroll
    for (int c = 0; c < 4; ++c) {
        #pragma unroll
        for (int s = 0; s < 4; ++s) {
            const int tt = (ROLE <= 1) ? 3 - s : s;     // inner order matches chain direction
            const int t  = (ROLE == 0) ? (12 - 4*c) + tt
                         : (ROLE == 1) ? (28 - 4*c) + tt
                         : (ROLE == 2) ? 32 + 4*c + tt
                         :               47 + 4*c + tt;
            if (ROLE == 2 && t > 46) continue;          // folds at compile time

            const float* Rl = L + lane*RSTR + tt*9;
            const float r0=Rl[0], r1=Rl[1], r2=Rl[2];
            const float r3=Rl[3], r4=Rl[4], r5=Rl[5];
            const float r6=Rl[6], r7=Rl[7], r8=Rl[8];
            #pragma unroll
            for (int row = 0; row < 3; ++row) {
                const float a0=M[3*row], a1=M[3*row+1], a2=M[3*row+2];
                float n0, n1, n2;
                if constexpr (ROLE <= 1) {      // M <- M @ R^T
                    n0 = a0*r0 + a1*r1 + a2*r2;
                    n1 = a0*r3 + a1*r4 + a2*r5;
                    n2 = a0*r6 + a1*r7 + a2*r8;
                } else {                        // M <- M @ R
                    n0 = a0*r0 + a1*r3 + a2*r6;
                    n1 = a0*r1 + a1*r4 + a2*r7;
                    n2 = a0*r2 + a1*r5 + a2*r8;
                }
                M[3*row]=n0; M[3*row+1]=n1; M[3*row+2]=n2;
            }
            const float wx = M[0]*dx + M[1]*dy + M[2]*dz;
            const float wy = M[3]*dx + M[4]*dy + M[5]*dz;
            const float wz = M[6]*dx + M[7]*dy + M[8]*dz;

            if constexpr (ROLE == 0) {
                PUT3(3*t, wx, wy, wz);                  // floats 0..47 (unfixed), t descending
                if (t == 10) flush16(orow + 32, bufE);  // sector 2 complete
                if (t == 5)  flush16(orow + 16, bufO);  // sector 1
                if (t == 0)  flush16(orow +  0, bufE);  // sector 0
            } else if constexpr (ROLE == 1) {
                PUT3(3*t, wx, wy, wz);                  // floats 48..95, t descending
                if (t == 26) flush16(orow + 80, bufO);  // sector 5
                if (t == 21) flush16(orow + 64, bufE);  // sector 4
                if (t == 16) flush16(orow + 48, bufO);  // sector 3
            } else if constexpr (ROLE == 2) {
                PUT3(3*t + 3, wx, wy, wz);              // floats 99..143, t ascending
                if (t == 36) flush16(orow +  96, bufE); // sector 6
                if (t == 41) flush16(orow + 112, bufO); // sector 7
                if (t == 46) flush16(orow + 128, bufE); // sector 8
            } else {
                PUT3(3*t + 3, wx, wy, wz);              // floats 144..191 (unfixed), t ascending
                if (t == 52) flush16(orow + 144, bufO); // sector 9
                if (t == 57) flush16(orow + 160, bufE); // sector 10
                if (t == 62) flush16(orow + 176, bufO); // sector 11
            }
        }
        if (c < 3) {
            lds_fence();                // chunk-c reads done before overwrite
            stw();                      // stage chunk c+1 (compiler inserts vmcnt wait)
            if (c < 2) issue(TBL[ROLE][c+2]);
            lds_fence();                // writes visible before next chunk's reads
        }
    }

    if constexpr (ROLE == 1 || ROLE == 2) {     // publish final matrix in own staging
        lds_fence();
        float* P = L + lane*RSTR;
        #pragma unroll
        for (int i = 0; i < 9; ++i) P[i] = M[i];
    }

    __syncthreads();    // each wave executes exactly one barrier

    if constexpr (ROLE == 0 || ROLE == 3) {
        // L2-hot round-trip fixup: own row, own lane -> same-thread RAW, coherent via L1/L2.
        const float* P = ldsAll + (ROLE == 0 ? 1 : 2) * WSPAN + lane*RSTR;
        const float m0=P[0], m1=P[1], m2=P[2];
        const float m3=P[3], m4=P[4], m5=P[5];
        const float m6=P[6], m7=P[7], m8=P[8];
        float* base = orow + (ROLE == 0 ? 0 : 144);
        #pragma unroll
        for (int g = 0; g < 4; ++g) {           // 12 floats = 4 vectors per group
            float4 a = *reinterpret_cast<const float4*>(base + 12*g + 0);
            float4 bq= *reinterpret_cast<const float4*>(base + 12*g + 4);
            float4 cq= *reinterpret_cast<const float4*>(base + 12*g + 8);
            const float x0=a.x,  y0=a.y,  z0=a.z;
            const float x1=a.w,  y1=bq.x, z1=bq.y;
            const float x2=bq.z, y2=bq.w, z2=cq.x;
            const float x3=cq.y, y3=cq.z, z3=cq.w;
            const float f0x=m0*x0+m1*y0+m2*z0, f0y=m3*x0+m4*y0+m5*z0, f0z=m6*x0+m7*y0+m8*z0;
            const float f1x=m0*x1+m1*y1+m2*z1, f1y=m3*x1+m4*y1+m5*z1, f1z=m6*x1+m7*y1+m8*z1;
            const float f2x=m0*x2+m1*y2+m2*z2, f2y=m3*x2+m4*y2+m5*z2, f2z=m6*x2+m7*y2+m8*z2;
            const float f3x=m0*x3+m1*y3+m2*z3, f3y=m3*x3+m4*y3+m5*z3, f3z=m6*x3+m7*y3+m8*z3;
            *reinterpret_cast<float4*>(base + 12*g + 0) = make_float4(f0x,f0y,f0z,f1x);
            *reinterpret_cast<float4*>(base + 12*g + 4) = make_float4(f1y,f1z,f2x,f2y);
            *reinterpret_cast<float4*>(base + 12*g + 8) = make_float4(f2z,f3x,f3y,f3z);
        }
    }
    #undef PUT3
}

__global__ __launch_bounds__(NTHR, 2) void gaze_kernel(
    const float* __restrict__ dirg, const float* __restrict__ Rg,
    float* __restrict__ outg)
{
    __shared__ float ldsR[4 * WSPAN];   // 37888 B -> 4 blocks/CU -> 16 waves/CU
    const int tid = threadIdx.x, wid = tid >> 6, lane = tid & 63;
    const int64_t b0 = (int64_t)blockIdx.x * BPB;
    if      (wid == 0) run_chain<0>(Rg, dirg, outg, b0, lane, ldsR);
    else if (wid == 1) run_chain<1>(Rg, dirg, outg, b0, lane, ldsR);
    else if (wid == 2) run_chain<2>(Rg, dirg, outg, b0, lane, ldsR);
    else               run_chain<3>(Rg, dirg, outg, b0, lane, ldsR);
}

// ---- kernel 2: LSTM over dirs[0..32] (row floats 0..98, post-fixup, L2/L3-warm); h -> 96..98
__global__ __launch_bounds__(64) void lstm_kernel(
    const float* __restrict__ w_ih, const float* __restrict__ w_hh,
    const float* __restrict__ b_ih, const float* __restrict__ b_hh,
    float* __restrict__ outg)
{
    __shared__ float sd[64 * 101];      // 64 rows x 100 floats (+1 pad)
    const int lane = threadIdx.x;       // one wave per block
    const int64_t b0 = (int64_t)blockIdx.x * 64;

    #pragma unroll
    for (int k = 0; k < 25; ++k) {      // 1600 float4: coalesced 400-B runs per row
        const int f4 = k*64 + lane, seg = f4/25, off = f4 - seg*25;
        const float4 v = *reinterpret_cast<const float4*>(outg + (b0+seg)*OUTF + off*4);
        float* p = sd + seg*101 + off*4;
        p[0]=v.x; p[1]=v.y; p[2]=v.z; p[3]=v.w;
    }
    lds_fence();

    float wi[12][3], wh[12][3], bs[12];
    #pragma unroll
    for (int g = 0; g < 12; ++g) {      // uniform -> scalar loads
        wi[g][0]=w_ih[g*3+0]; wi[g][1]=w_ih[g*3+1]; wi[g][2]=w_ih[g*3+2];
        wh[g][0]=w_hh[g*3+0]; wh[g][1]=w_hh[g*3+1]; wh[g][2]=w_hh[g*3+2];
        bs[g]   = b_ih[g] + b_hh[g];
    }

    const float* x = sd + lane*101;     // stride 101: lane*5 mod 32 -> conflict-free
    float h[3]  = {0.f,0.f,0.f};
    float cc[3] = {0.f,0.f,0.f};
    #pragma unroll
    for (int t = 0; t < 33; ++t) {
        const float x0 = x[3*t], x1 = x[3*t+1], x2 = x[3*t+2];
        float ga[12];
        #pragma unroll
        for (int g = 0; g < 12; ++g)
            ga[g] = bs[g] + wi[g][0]*x0 + wi[g][1]*x1 + wi[g][2]*x2
                          + wh[g][0]*h[0] + wh[g][1]*h[1] + wh[g][2]*h[2];
        float ig[3], fg[3], gg[3], og[3];
        #pragma unroll
        for (int j = 0; j < 3; ++j) {
            ig[j] = sigm_(ga[j]);
            fg[j] = sigm_(ga[3+j]);
            gg[j] = tanh_(ga[6+j]);
            og[j] = sigm_(ga[9+j]);
        }
        #pragma unroll
        for (int j = 0; j < 3; ++j) {
            cc[j] = fg[j]*cc[j] + ig[j]*gg[j];
            h[j]  = og[j]*tanh_(cc[j]);
        }
    }

    float* row = outg + (b0 + lane) * OUTF;
    row[96] = h[0]; row[97] = h[1]; row[98] = h[2];
}

}  // namespace

extern "C" void kernel_launch(void* const* d_in, const int* in_sizes, int n_in,
                              void* d_out, int out_size, void* d_ws, size_t ws_size,
                              hipStream_t stream) {
    const float* dirg = (const float*)d_in[0];
    const float* Rg   = (const float*)d_in[1];
    // d_in[2] = S_diag: unused by the reference forward
    const float* wih  = (const float*)d_in[3];
    const float* whh  = (const float*)d_in[4];
    const float* bih  = (const float*)d_in[5];
    const float* bhh  = (const float*)d_in[6];
    float* outg = (float*)d_out;

    const int B = in_sizes[0] / 3;      // 65536
    gaze_kernel<<<B / BPB, NTHR, 0, stream>>>(dirg, Rg, outg);
    lstm_kernel<<<B / 64, 64, 0, stream>>>(wih, whh, bih, bhh, outg);
}